// Round 7
// baseline (124.013 us; speedup 1.0000x reference)
//
#include <hip/hip_runtime.h>
#include <hip/hip_bf16.h>
#include <math.h>

#define MDIM 1024
#define QTOT 65536
#define KTOP 16
#define ODIM 256
#define FDIM 512
#define TTILES 4

typedef float f32x4 __attribute__((ext_vector_type(4)));
typedef short s16x8 __attribute__((ext_vector_type(8)));
typedef unsigned u32x4 __attribute__((ext_vector_type(4)));

#if __has_builtin(__builtin_amdgcn_exp2f)
#define EXP2(x) __builtin_amdgcn_exp2f(x)
#else
#define EXP2(x) exp2f(x)
#endif

// pinned single-instruction min/max
#define VMIN(a,b)    ({float r_; asm("v_min_f32 %0,%1,%2":"=v"(r_):"v"(a),"v"(b)); r_;})
#define VMAX(a,b)    ({float r_; asm("v_max_f32 %0,%1,%2":"=v"(r_):"v"(a),"v"(b)); r_;})

__device__ __forceinline__ int read_mask(const void* m, int i, bool is8) {
  return is8 ? (int)((const unsigned char*)m)[i] : ((const int*)m)[i];
}

__device__ __forceinline__ unsigned pack2(float lo, float hi) {
  __hip_bfloat162 h = __float22bfloat162_rn(make_float2(lo, hi));
  unsigned u;
  __builtin_memcpy(&u, &h, sizeof(u));
  return u;
}

// ---------------- kernel 1: top-16 neighbor distances ----------------
// grid: QTOT/32 blocks x 256 threads. Block = 32 queries of one batch,
// 8 lanes per query. Selection: sort8 network + bitonic merge into sorted-16.
__global__ __launch_bounds__(256, 6) void topk_kernel(
    const float* __restrict__ coords, const void* __restrict__ mask,
    float* __restrict__ dists)
{
  __shared__ float4 pts[MDIM + 8];   // +8 pad: last-group overreads are poisoned
  __shared__ int posof[MDIM];        // atom -> compacted position (-1 if masked)
  __shared__ int s_cnt;
  __shared__ int s_is8;
  const int tid = threadIdx.x;
  const int lane = tid & 63;
  const int wv = tid >> 6;
  const int bid = blockIdx.x;
  const int batch = bid >> 5;      // 32 blocks per batch
  const int qchunk = bid & 31;

  if (tid == 0) { s_cnt = 0; s_is8 = 0; }
  __syncthreads();
  { // mask dtype detection: int32 0/1 words vs packed int8 bools
    unsigned w = ((const unsigned*)mask)[tid & 255];
    if (w > 1u) atomicOr(&s_is8, 1);
  }
  __syncthreads();
  const bool is8 = (s_is8 != 0);

  const float* cb = coords + (size_t)batch * MDIM * 3;
  const int mbase = batch * MDIM;

  // compact valid atoms into LDS: (x,y,z,|p|^2)
  #pragma unroll
  for (int r = 0; r < 4; ++r) {
    int a = r * 256 + tid;
    int v = read_mask(mask, mbase + a, is8);
    float x = cb[a*3+0], y = cb[a*3+1], z = cb[a*3+2];
    float S = fmaf(z, z, fmaf(y, y, x * x));
    unsigned long long bal = __ballot(v != 0);
    int base = 0;
    if (lane == 0) base = atomicAdd(&s_cnt, __popcll(bal));
    base = __shfl(base, 0);
    int pos = base + __popcll(bal & ((1ull << lane) - 1ull));
    if (v) {
      float4 p; p.x = x; p.y = y; p.z = z; p.w = S;
      pts[pos] = p;
    }
    posof[a] = v ? pos : -1;
  }
  __syncthreads();
  const int cnt = s_cnt;

  // 8 lanes per query: lane = qi + 8*part
  const int qi = lane & 7;
  const int part = lane >> 3;
  const int qlocal = qchunk * 32 + wv * 8 + qi;
  const float qx = cb[qlocal*3+0], qy = cb[qlocal*3+1], qz = cb[qlocal*3+2];
  const float Q = fmaf(qz, qz, fmaf(qy, qy, qx * qx));
  const float m2x = -2.0f * qx, m2y = -2.0f * qy, m2z = -2.0f * qz;
  const int selfpos = posof[qlocal];
  const int lo = (cnt * part) >> 3;
  const int hi = (cnt * (part + 1)) >> 3;

  float t[16];
  #pragma unroll
  for (int i = 0; i < 16; ++i) t[i] = 3.0e38f;

  const int len = hi - lo;
  const int ng = (len + 7) >> 3;
  for (int g = 0; g < ng; ++g) {
    const int base = lo + g * 8;
    float s[8];
    #pragma unroll
    for (int i = 0; i < 8; ++i) {
      int idx = base + i;
      float4 p = pts[idx];
      // d' = |p|^2 - 2 q.p  (= d^2 - Q, order-preserving)
      float d = fmaf(p.z, m2z, fmaf(p.y, m2y, fmaf(p.x, m2x, p.w)));
      d = (idx == selfpos) ? 3.0e38f : d;   // exclude self
      s[i] = (idx < hi) ? d : 3.0e38f;      // ragged-tail poison
    }
    // Batcher sort-8 (19 CE)
    #define CES(i,j) { float mn_ = VMIN(s[i], s[j]); float mx_ = VMAX(s[i], s[j]); s[i] = mn_; s[j] = mx_; }
    CES(0,1) CES(2,3) CES(4,5) CES(6,7)
    CES(0,2) CES(1,3) CES(4,6) CES(5,7)
    CES(1,2) CES(5,6)
    CES(0,4) CES(1,5) CES(2,6) CES(3,7)
    CES(2,4) CES(3,5)
    CES(1,2) CES(3,4) CES(5,6)
    #undef CES
    // half-clean: t[8..15] vs reversed s  -> t becomes bitonic, holds 16 smallest
    #pragma unroll
    for (int i = 0; i < 8; ++i) t[8 + i] = VMIN(t[8 + i], s[7 - i]);
    // bitonic clean of 16
    #define CET(i,j) { float mn_ = VMIN(t[i], t[j]); float mx_ = VMAX(t[i], t[j]); t[i] = mn_; t[j] = mx_; }
    CET(0,8) CET(1,9) CET(2,10) CET(3,11) CET(4,12) CET(5,13) CET(6,14) CET(7,15)
    CET(0,4) CET(1,5) CET(2,6)  CET(3,7)  CET(8,12) CET(9,13) CET(10,14) CET(11,15)
    CET(0,2) CET(1,3) CET(4,6)  CET(5,7)  CET(8,10) CET(9,11) CET(12,14) CET(13,15)
    CET(0,1) CET(2,3) CET(4,5)  CET(6,7)  CET(8,9)  CET(10,11) CET(12,13) CET(14,15)
    #undef CET
  }

  // merge the 8 part-lists: bitonic merges with partners ^8, ^16, ^32
  #pragma unroll
  for (int stepi = 0; stepi < 3; ++stepi) {
    const int step = 8 << stepi;
    float o_[16], m[16];
    #pragma unroll
    for (int i = 0; i < 16; ++i) o_[i] = __shfl(t[i], lane ^ step);
    #pragma unroll
    for (int i = 0; i < 16; ++i) m[i] = VMIN(t[i], o_[15 - i]);
    #define CE(i,jj) { float a_ = VMIN(m[i], m[jj]); float b_ = VMAX(m[i], m[jj]); m[i] = a_; m[jj] = b_; }
    CE(0,8) CE(1,9) CE(2,10) CE(3,11) CE(4,12) CE(5,13) CE(6,14) CE(7,15)
    CE(0,4) CE(1,5) CE(2,6)  CE(3,7)  CE(8,12) CE(9,13) CE(10,14) CE(11,15)
    CE(0,2) CE(1,3) CE(4,6)  CE(5,7)  CE(8,10) CE(9,11) CE(12,14) CE(13,15)
    CE(0,1) CE(2,3) CE(4,5)  CE(6,7)  CE(8,9)  CE(10,11) CE(12,13) CE(14,15)
    #undef CE
    #pragma unroll
    for (int i = 0; i < 16; ++i) t[i] = m[i];
  }

  if (part == 0) {
    int mq = read_mask(mask, mbase + qlocal, is8);
    float res[16];
    #pragma unroll
    for (int i = 0; i < 16; ++i) {
      float v = t[i];
      float d = (v > 1.0e37f) ? 24.0f : sqrtf(fmaxf(v + Q, 1e-12f)); // pad -> MAX_DIST
      res[i] = mq ? d : -1.0f;   // -1 sentinel => output row forced to zero
    }
    float4* dst = (float4*)(dists + (size_t)(mbase + qlocal) * KTOP);
    float4 o0, o1, o2, o3;
    o0.x=res[0];  o0.y=res[1];  o0.z=res[2];  o0.w=res[3];
    o1.x=res[4];  o1.y=res[5];  o1.z=res[6];  o1.w=res[7];
    o2.x=res[8];  o2.y=res[9];  o2.z=res[10]; o2.w=res[11];
    o3.x=res[12]; o3.y=res[13]; o3.z=res[14]; o3.w=res[15];
    dst[0]=o0; dst[1]=o1; dst[2]=o2; dst[3]=o3;
  }
}

// ---------------- kernel 2: fused RBF + projection (bf16 MFMA) ----------------
// grid: (2 n-blocks, QTOT/128 m-blocks) x 256 threads (4 waves).
// Single-buffer A tile (33 KB) -> 4 blocks/CU. W frags as MFMA A operand:
// each wave writes one full 128B line per output row, THROUGH L2 (no NT —
// NT partial-line streaming caused 2x write amplification + RMW fetch).
constexpr double SPd = 24.0 / 31.0;
constexpr double SP2d = SPd * SPd;
constexpr float ALPHA = (float)(-(SP2d / (SP2d + 1e-8)) * 1.4426950408889634);
constexpr float INV_SP = (float)(1.0 / SPd);

__device__ __forceinline__ void gen_tile(u32x4 (*Abuf)[1040], int row0, int s,
                                         float d0, float d1) {
  float dd0 = (d0 < 0.f) ? 1.0e9f : d0;   // sentinel -> rbf == 0
  float dd1 = (d1 < 0.f) ? 1.0e9f : d1;
  #pragma unroll
  for (int i = 0; i < 2; ++i) {
    float d = i ? dd1 : dd0;
    float u = d * INV_SP;
    float C1 = (-2.0f * ALPHA) * u;
    float C0 = ALPHA * u * u;
    #pragma unroll
    for (int c8 = 0; c8 < 4; ++c8) {
      u32x4 ch;
      #pragma unroll
      for (int q = 0; q < 4; ++q) {
        const int j0 = c8 * 8 + q * 2;
        float e0 = EXP2(fmaf(C1, (float)j0,       C0) + ALPHA * (float)(j0 * j0));
        float e1 = EXP2(fmaf(C1, (float)(j0 + 1), C0) + ALPHA * (float)((j0 + 1) * (j0 + 1)));
        ch[q] = pack2(e0, e1);
      }
      Abuf[i][s * 65 + c8 * 16 + row0] = ch;
    }
  }
}

__global__ __launch_bounds__(256, 4) void rbf_gemm_kernel(
    const float* __restrict__ dists, const float* __restrict__ W,
    float* __restrict__ out)
{
  __shared__ u32x4 A_sh[2][1040];   // [row-half][s*65 + fragslot], single-buffered

  const int tid = threadIdx.x;
  const int lane = tid & 63;
  const int wv = tid >> 6;
  const int c0 = blockIdx.x * 128 + wv * 32 + (lane & 15);
  const int ksub = (lane >> 4) * 8;

  // preload W fragments for 2 col-sets (used as MFMA A operand; m = W col)
  s16x8 bf0[16], bf1[16];
  const float* wr0 = W + (size_t)c0 * FDIM;
  const float* wr1 = wr0 + (size_t)16 * FDIM;
  #pragma unroll
  for (int s = 0; s < 16; ++s) {
    const float4* p0 = (const float4*)(wr0 + s * 32 + ksub);
    const float4* p1 = (const float4*)(wr1 + s * 32 + ksub);
    float4 a = p0[0], b = p0[1], c = p1[0], d = p1[1];
    u32x4 u0, u1;
    u0[0] = pack2(a.x, a.y); u0[1] = pack2(a.z, a.w);
    u0[2] = pack2(b.x, b.y); u0[3] = pack2(b.z, b.w);
    u1[0] = pack2(c.x, c.y); u1[1] = pack2(c.z, c.w);
    u1[2] = pack2(d.x, d.y); u1[3] = pack2(d.z, d.w);
    __builtin_memcpy(&bf0[s], &u0, sizeof(u0));
    __builtin_memcpy(&bf1[s], &u1, sizeof(u1));
  }

  const int row0 = tid >> 4;       // gen cell: row (and row+16), slot
  const int sgen = tid & 15;
  const int qbase0 = blockIdx.y * (32 * TTILES);
  const size_t dbase = (size_t)qbase0 * KTOP;

  float n0 = dists[dbase + tid];
  float n1 = dists[dbase + 256 + tid];

  for (int t = 0; t < TTILES; ++t) {
    gen_tile(A_sh, row0, sgen, n0, n1);
    if (t + 1 < TTILES) {
      n0 = dists[dbase + (size_t)(t + 1) * 512 + tid];
      n1 = dists[dbase + (size_t)(t + 1) * 512 + 256 + tid];
    }
    __syncthreads();

    f32x4 acc00 = {0.f,0.f,0.f,0.f}, acc01 = {0.f,0.f,0.f,0.f};
    f32x4 acc10 = {0.f,0.f,0.f,0.f}, acc11 = {0.f,0.f,0.f,0.f};
    #pragma unroll
    for (int s = 0; s < 16; ++s) {
      s16x8 a0, a1;
      u32x4 ra0 = A_sh[0][s * 65 + lane];
      u32x4 ra1 = A_sh[1][s * 65 + lane];
      __builtin_memcpy(&a0, &ra0, sizeof(ra0));
      __builtin_memcpy(&a1, &ra1, sizeof(ra1));
      // W as A (m = out col), rbf as B (n = out row)
      acc00 = __builtin_amdgcn_mfma_f32_16x16x32_bf16(bf0[s], a0, acc00, 0, 0, 0);
      acc01 = __builtin_amdgcn_mfma_f32_16x16x32_bf16(bf1[s], a0, acc01, 0, 0, 0);
      acc10 = __builtin_amdgcn_mfma_f32_16x16x32_bf16(bf0[s], a1, acc10, 0, 0, 0);
      acc11 = __builtin_amdgcn_mfma_f32_16x16x32_bf16(bf1[s], a1, acc11, 0, 0, 0);
    }

    const int qbase = qbase0 + t * 32;
    const int qr = lane & 15;                       // out row (n)
    const int colb = blockIdx.x * 128 + wv * 32 + (lane >> 4) * 4;  // out col base
    float* o0 = out + (size_t)(qbase + qr) * ODIM + colb;
    float* o1 = out + (size_t)(qbase + 16 + qr) * ODIM + colb;
    *(f32x4*)o0 = acc00;
    *(f32x4*)(o0 + 16) = acc01;
    *(f32x4*)o1 = acc10;
    *(f32x4*)(o1 + 16) = acc11;
    __syncthreads();   // protect next gen's overwrite
  }
}

extern "C" void kernel_launch(void* const* d_in, const int* in_sizes, int n_in,
                              void* d_out, int out_size, void* d_ws, size_t ws_size,
                              hipStream_t stream) {
  const float* coords = (const float*)d_in[0];
  const void* mask = d_in[1];
  const float* W = (const float*)d_in[2];
  float* out = (float*)d_out;
  float* dists = (float*)d_ws;   // QTOT * 16 fp32 = 4 MB scratch

  hipLaunchKernelGGL(topk_kernel, dim3(QTOT / 32), dim3(256), 0, stream,
                     coords, mask, dists);
  hipLaunchKernelGGL(rbf_gemm_kernel, dim3(2, QTOT / (32 * TTILES)), dim3(256), 0, stream,
                     dists, W, out);
}

// Round 8
// 114.277 us; speedup vs baseline: 1.0852x; 1.0852x over previous
//
#include <hip/hip_runtime.h>
#include <hip/hip_bf16.h>
#include <math.h>

#define MDIM 1024
#define QTOT 65536
#define KTOP 16
#define ODIM 256
#define FDIM 512
#define TTILES 4

typedef float f32x4 __attribute__((ext_vector_type(4)));
typedef short s16x8 __attribute__((ext_vector_type(8)));
typedef unsigned u32x4 __attribute__((ext_vector_type(4)));

#if __has_builtin(__builtin_amdgcn_exp2f)
#define EXP2(x) __builtin_amdgcn_exp2f(x)
#else
#define EXP2(x) exp2f(x)
#endif

// pinned single-instruction min/max
#define VMIN(a,b)    ({float r_; asm("v_min_f32 %0,%1,%2":"=v"(r_):"v"(a),"v"(b)); r_;})
#define VMAX(a,b)    ({float r_; asm("v_max_f32 %0,%1,%2":"=v"(r_):"v"(a),"v"(b)); r_;})

__device__ __forceinline__ int read_mask(const void* m, int i, bool is8) {
  return is8 ? (int)((const unsigned char*)m)[i] : ((const int*)m)[i];
}

__device__ __forceinline__ unsigned pack2(float lo, float hi) {
  __hip_bfloat162 h = __float22bfloat162_rn(make_float2(lo, hi));
  unsigned u;
  __builtin_memcpy(&u, &h, sizeof(u));
  return u;
}

// ---------------- kernel 1: top-16 neighbor distances ----------------
// grid: QTOT/32 blocks x 256 threads. Block = 32 queries of one batch,
// 8 lanes per query. Selection: sort8 network + bitonic merge into sorted-16.
__global__ __launch_bounds__(256, 6) void topk_kernel(
    const float* __restrict__ coords, const void* __restrict__ mask,
    float* __restrict__ dists)
{
  __shared__ float4 pts[MDIM + 8];   // +8 pad: last-group overreads are poisoned
  __shared__ int posof[MDIM];        // atom -> compacted position (-1 if masked)
  __shared__ int s_cnt;
  __shared__ int s_is8;
  const int tid = threadIdx.x;
  const int lane = tid & 63;
  const int wv = tid >> 6;
  const int bid = blockIdx.x;
  const int batch = bid >> 5;      // 32 blocks per batch
  const int qchunk = bid & 31;

  if (tid == 0) { s_cnt = 0; s_is8 = 0; }
  __syncthreads();
  { // mask dtype detection: int32 0/1 words vs packed int8 bools
    unsigned w = ((const unsigned*)mask)[tid & 255];
    if (w > 1u) atomicOr(&s_is8, 1);
  }
  __syncthreads();
  const bool is8 = (s_is8 != 0);

  const float* cb = coords + (size_t)batch * MDIM * 3;
  const int mbase = batch * MDIM;

  // compact valid atoms into LDS: (x,y,z,|p|^2)
  #pragma unroll
  for (int r = 0; r < 4; ++r) {
    int a = r * 256 + tid;
    int v = read_mask(mask, mbase + a, is8);
    float x = cb[a*3+0], y = cb[a*3+1], z = cb[a*3+2];
    float S = fmaf(z, z, fmaf(y, y, x * x));
    unsigned long long bal = __ballot(v != 0);
    int base = 0;
    if (lane == 0) base = atomicAdd(&s_cnt, __popcll(bal));
    base = __shfl(base, 0);
    int pos = base + __popcll(bal & ((1ull << lane) - 1ull));
    if (v) {
      float4 p; p.x = x; p.y = y; p.z = z; p.w = S;
      pts[pos] = p;
    }
    posof[a] = v ? pos : -1;
  }
  __syncthreads();
  const int cnt = s_cnt;

  // 8 lanes per query: lane = qi + 8*part
  const int qi = lane & 7;
  const int part = lane >> 3;
  const int qlocal = qchunk * 32 + wv * 8 + qi;
  const float qx = cb[qlocal*3+0], qy = cb[qlocal*3+1], qz = cb[qlocal*3+2];
  const float Q = fmaf(qz, qz, fmaf(qy, qy, qx * qx));
  const float m2x = -2.0f * qx, m2y = -2.0f * qy, m2z = -2.0f * qz;
  const int selfpos = posof[qlocal];
  const int lo = (cnt * part) >> 3;
  const int hi = (cnt * (part + 1)) >> 3;

  float t[16];
  #pragma unroll
  for (int i = 0; i < 16; ++i) t[i] = 3.0e38f;

  const int len = hi - lo;
  const int ng = (len + 7) >> 3;
  for (int g = 0; g < ng; ++g) {
    const int base = lo + g * 8;
    float s[8];
    #pragma unroll
    for (int i = 0; i < 8; ++i) {
      int idx = base + i;
      float4 p = pts[idx];
      // d' = |p|^2 - 2 q.p  (= d^2 - Q, order-preserving)
      float d = fmaf(p.z, m2z, fmaf(p.y, m2y, fmaf(p.x, m2x, p.w)));
      d = (idx == selfpos) ? 3.0e38f : d;   // exclude self
      s[i] = (idx < hi) ? d : 3.0e38f;      // ragged-tail poison
    }
    // Batcher sort-8 (19 CE)
    #define CES(i,j) { float mn_ = VMIN(s[i], s[j]); float mx_ = VMAX(s[i], s[j]); s[i] = mn_; s[j] = mx_; }
    CES(0,1) CES(2,3) CES(4,5) CES(6,7)
    CES(0,2) CES(1,3) CES(4,6) CES(5,7)
    CES(1,2) CES(5,6)
    CES(0,4) CES(1,5) CES(2,6) CES(3,7)
    CES(2,4) CES(3,5)
    CES(1,2) CES(3,4) CES(5,6)
    #undef CES
    // half-clean: t[8..15] vs reversed s  -> t becomes bitonic, holds 16 smallest
    #pragma unroll
    for (int i = 0; i < 8; ++i) t[8 + i] = VMIN(t[8 + i], s[7 - i]);
    // bitonic clean of 16
    #define CET(i,j) { float mn_ = VMIN(t[i], t[j]); float mx_ = VMAX(t[i], t[j]); t[i] = mn_; t[j] = mx_; }
    CET(0,8) CET(1,9) CET(2,10) CET(3,11) CET(4,12) CET(5,13) CET(6,14) CET(7,15)
    CET(0,4) CET(1,5) CET(2,6)  CET(3,7)  CET(8,12) CET(9,13) CET(10,14) CET(11,15)
    CET(0,2) CET(1,3) CET(4,6)  CET(5,7)  CET(8,10) CET(9,11) CET(12,14) CET(13,15)
    CET(0,1) CET(2,3) CET(4,5)  CET(6,7)  CET(8,9)  CET(10,11) CET(12,13) CET(14,15)
    #undef CET
  }

  // merge the 8 part-lists: bitonic merges with partners ^8, ^16, ^32
  #pragma unroll
  for (int stepi = 0; stepi < 3; ++stepi) {
    const int step = 8 << stepi;
    float o_[16], m[16];
    #pragma unroll
    for (int i = 0; i < 16; ++i) o_[i] = __shfl(t[i], lane ^ step);
    #pragma unroll
    for (int i = 0; i < 16; ++i) m[i] = VMIN(t[i], o_[15 - i]);
    #define CE(i,jj) { float a_ = VMIN(m[i], m[jj]); float b_ = VMAX(m[i], m[jj]); m[i] = a_; m[jj] = b_; }
    CE(0,8) CE(1,9) CE(2,10) CE(3,11) CE(4,12) CE(5,13) CE(6,14) CE(7,15)
    CE(0,4) CE(1,5) CE(2,6)  CE(3,7)  CE(8,12) CE(9,13) CE(10,14) CE(11,15)
    CE(0,2) CE(1,3) CE(4,6)  CE(5,7)  CE(8,10) CE(9,11) CE(12,14) CE(13,15)
    CE(0,1) CE(2,3) CE(4,5)  CE(6,7)  CE(8,9)  CE(10,11) CE(12,13) CE(14,15)
    #undef CE
    #pragma unroll
    for (int i = 0; i < 16; ++i) t[i] = m[i];
  }

  if (part == 0) {
    int mq = read_mask(mask, mbase + qlocal, is8);
    float res[16];
    #pragma unroll
    for (int i = 0; i < 16; ++i) {
      float v = t[i];
      float d = (v > 1.0e37f) ? 24.0f : sqrtf(fmaxf(v + Q, 1e-12f)); // pad -> MAX_DIST
      res[i] = mq ? d : -1.0f;   // -1 sentinel => output row forced to zero
    }
    float4* dst = (float4*)(dists + (size_t)(mbase + qlocal) * KTOP);
    float4 o0, o1, o2, o3;
    o0.x=res[0];  o0.y=res[1];  o0.z=res[2];  o0.w=res[3];
    o1.x=res[4];  o1.y=res[5];  o1.z=res[6];  o1.w=res[7];
    o2.x=res[8];  o2.y=res[9];  o2.z=res[10]; o2.w=res[11];
    o3.x=res[12]; o3.y=res[13]; o3.z=res[14]; o3.w=res[15];
    dst[0]=o0; dst[1]=o1; dst[2]=o2; dst[3]=o3;
  }
}

// ---------------- kernel 2: fused RBF + projection (bf16 MFMA) ----------------
// grid: (2 n-blocks, QTOT/128 m-blocks) x 256 threads (4 waves).
// rbf frags as MFMA A operand, W frags as B -> D layout: col(lane&15)=out COL.
// Consecutive LANES write consecutive addresses (64B runs per 16-lane group):
// the strided-lane dwordx4 pattern (R4-R7) caused 2x WRITE + output FETCH
// (TCC sector RMW); this scalar adjacent-lane pattern measured clean in R2.
constexpr double SPd = 24.0 / 31.0;
constexpr double SP2d = SPd * SPd;
constexpr float ALPHA = (float)(-(SP2d / (SP2d + 1e-8)) * 1.4426950408889634);
constexpr float INV_SP = (float)(1.0 / SPd);

__device__ __forceinline__ void gen_tile(u32x4 (*Abuf)[1040], int row0, int s,
                                         float d0, float d1) {
  float dd0 = (d0 < 0.f) ? 1.0e9f : d0;   // sentinel -> rbf == 0
  float dd1 = (d1 < 0.f) ? 1.0e9f : d1;
  #pragma unroll
  for (int i = 0; i < 2; ++i) {
    float d = i ? dd1 : dd0;
    float u = d * INV_SP;
    float C1 = (-2.0f * ALPHA) * u;
    float C0 = ALPHA * u * u;
    #pragma unroll
    for (int c8 = 0; c8 < 4; ++c8) {
      u32x4 ch;
      #pragma unroll
      for (int q = 0; q < 4; ++q) {
        const int j0 = c8 * 8 + q * 2;
        float e0 = EXP2(fmaf(C1, (float)j0,       C0) + ALPHA * (float)(j0 * j0));
        float e1 = EXP2(fmaf(C1, (float)(j0 + 1), C0) + ALPHA * (float)((j0 + 1) * (j0 + 1)));
        ch[q] = pack2(e0, e1);
      }
      Abuf[i][s * 65 + c8 * 16 + row0] = ch;
    }
  }
}

__global__ __launch_bounds__(256, 4) void rbf_gemm_kernel(
    const float* __restrict__ dists, const float* __restrict__ W,
    float* __restrict__ out)
{
  __shared__ u32x4 A_sh[2][1040];   // [row-half][s*65 + fragslot], single-buffered

  const int tid = threadIdx.x;
  const int lane = tid & 63;
  const int wv = tid >> 6;
  const int c0 = blockIdx.x * 128 + wv * 32 + (lane & 15);
  const int ksub = (lane >> 4) * 8;

  // preload W fragments for 2 col-sets (MFMA B operand; n = out col)
  s16x8 bf0[16], bf1[16];
  const float* wr0 = W + (size_t)c0 * FDIM;
  const float* wr1 = wr0 + (size_t)16 * FDIM;
  #pragma unroll
  for (int s = 0; s < 16; ++s) {
    const float4* p0 = (const float4*)(wr0 + s * 32 + ksub);
    const float4* p1 = (const float4*)(wr1 + s * 32 + ksub);
    float4 a = p0[0], b = p0[1], c = p1[0], d = p1[1];
    u32x4 u0, u1;
    u0[0] = pack2(a.x, a.y); u0[1] = pack2(a.z, a.w);
    u0[2] = pack2(b.x, b.y); u0[3] = pack2(b.z, b.w);
    u1[0] = pack2(c.x, c.y); u1[1] = pack2(c.z, c.w);
    u1[2] = pack2(d.x, d.y); u1[3] = pack2(d.z, d.w);
    __builtin_memcpy(&bf0[s], &u0, sizeof(u0));
    __builtin_memcpy(&bf1[s], &u1, sizeof(u1));
  }

  const int row0 = tid >> 4;       // gen cell: row (and row+16), slot
  const int sgen = tid & 15;
  const int qbase0 = blockIdx.y * (32 * TTILES);
  const size_t dbase = (size_t)qbase0 * KTOP;

  float n0 = dists[dbase + tid];
  float n1 = dists[dbase + 256 + tid];

  for (int t = 0; t < TTILES; ++t) {
    gen_tile(A_sh, row0, sgen, n0, n1);
    if (t + 1 < TTILES) {
      n0 = dists[dbase + (size_t)(t + 1) * 512 + tid];
      n1 = dists[dbase + (size_t)(t + 1) * 512 + 256 + tid];
    }
    __syncthreads();

    f32x4 acc00 = {0.f,0.f,0.f,0.f}, acc01 = {0.f,0.f,0.f,0.f};
    f32x4 acc10 = {0.f,0.f,0.f,0.f}, acc11 = {0.f,0.f,0.f,0.f};
    #pragma unroll
    for (int s = 0; s < 16; ++s) {
      s16x8 a0, a1;
      u32x4 ra0 = A_sh[0][s * 65 + lane];
      u32x4 ra1 = A_sh[1][s * 65 + lane];
      __builtin_memcpy(&a0, &ra0, sizeof(ra0));
      __builtin_memcpy(&a1, &ra1, sizeof(ra1));
      // rbf as A (m = out row), W as B (n = out col)
      acc00 = __builtin_amdgcn_mfma_f32_16x16x32_bf16(a0, bf0[s], acc00, 0, 0, 0);
      acc01 = __builtin_amdgcn_mfma_f32_16x16x32_bf16(a0, bf1[s], acc01, 0, 0, 0);
      acc10 = __builtin_amdgcn_mfma_f32_16x16x32_bf16(a1, bf0[s], acc10, 0, 0, 0);
      acc11 = __builtin_amdgcn_mfma_f32_16x16x32_bf16(a1, bf1[s], acc11, 0, 0, 0);
    }

    // D layout: col = lane&15 (out col), row = (lane>>4)*4 + reg (out row)
    const int qbase = qbase0 + t * 32;
    const int rb = (lane >> 4) * 4;
    #pragma unroll
    for (int r = 0; r < 4; ++r) {
      out[(size_t)(qbase + rb + r) * ODIM + c0]           = acc00[r];
      out[(size_t)(qbase + rb + r) * ODIM + c0 + 16]      = acc01[r];
      out[(size_t)(qbase + 16 + rb + r) * ODIM + c0]      = acc10[r];
      out[(size_t)(qbase + 16 + rb + r) * ODIM + c0 + 16] = acc11[r];
    }
    __syncthreads();   // protect next gen's overwrite
  }
}

extern "C" void kernel_launch(void* const* d_in, const int* in_sizes, int n_in,
                              void* d_out, int out_size, void* d_ws, size_t ws_size,
                              hipStream_t stream) {
  const float* coords = (const float*)d_in[0];
  const void* mask = d_in[1];
  const float* W = (const float*)d_in[2];
  float* out = (float*)d_out;
  float* dists = (float*)d_ws;   // QTOT * 16 fp32 = 4 MB scratch

  hipLaunchKernelGGL(topk_kernel, dim3(QTOT / 32), dim3(256), 0, stream,
                     coords, mask, dists);
  hipLaunchKernelGGL(rbf_gemm_kernel, dim3(2, QTOT / (32 * TTILES)), dim3(256), 0, stream,
                     dists, W, out);
}

// Round 9
// 84.556 us; speedup vs baseline: 1.4666x; 1.3515x over previous
//
#include <hip/hip_runtime.h>
#include <hip/hip_bf16.h>
#include <math.h>

#define MDIM 1024
#define QTOT 65536
#define KTOP 16
#define ODIM 256
#define FDIM 512
#define TTILES 4

typedef float f32x4 __attribute__((ext_vector_type(4)));
typedef short s16x8 __attribute__((ext_vector_type(8)));
typedef unsigned u32x4 __attribute__((ext_vector_type(4)));

#if __has_builtin(__builtin_amdgcn_exp2f)
#define EXP2(x) __builtin_amdgcn_exp2f(x)
#else
#define EXP2(x) exp2f(x)
#endif

// pinned single-instruction min/max
#define VMIN(a,b)    ({float r_; asm("v_min_f32 %0,%1,%2":"=v"(r_):"v"(a),"v"(b)); r_;})
#define VMAX(a,b)    ({float r_; asm("v_max_f32 %0,%1,%2":"=v"(r_):"v"(a),"v"(b)); r_;})

__device__ __forceinline__ int read_mask(const void* m, int i, bool is8) {
  return is8 ? (int)((const unsigned char*)m)[i] : ((const int*)m)[i];
}

__device__ __forceinline__ unsigned pack2(float lo, float hi) {
  __hip_bfloat162 h = __float22bfloat162_rn(make_float2(lo, hi));
  unsigned u;
  __builtin_memcpy(&u, &h, sizeof(u));
  return u;
}

// ---------------- kernel 1: top-16 neighbor distances ----------------
// grid: QTOT/32 blocks x 256 threads. Block = 32 queries of one batch,
// 8 lanes per query. Selection: sort8 network + bitonic merge into sorted-16.
__global__ __launch_bounds__(256, 6) void topk_kernel(
    const float* __restrict__ coords, const void* __restrict__ mask,
    float* __restrict__ dists)
{
  __shared__ float4 pts[MDIM + 8];   // +8 pad: last-group overreads are poisoned
  __shared__ int posof[MDIM];        // atom -> compacted position (-1 if masked)
  __shared__ int s_cnt;
  __shared__ int s_is8;
  const int tid = threadIdx.x;
  const int lane = tid & 63;
  const int wv = tid >> 6;
  const int bid = blockIdx.x;
  const int batch = bid >> 5;      // 32 blocks per batch
  const int qchunk = bid & 31;

  if (tid == 0) { s_cnt = 0; s_is8 = 0; }
  __syncthreads();
  { // mask dtype detection: int32 0/1 words vs packed int8 bools
    unsigned w = ((const unsigned*)mask)[tid & 255];
    if (w > 1u) atomicOr(&s_is8, 1);
  }
  __syncthreads();
  const bool is8 = (s_is8 != 0);

  const float* cb = coords + (size_t)batch * MDIM * 3;
  const int mbase = batch * MDIM;

  // compact valid atoms into LDS: (x,y,z,|p|^2)
  #pragma unroll
  for (int r = 0; r < 4; ++r) {
    int a = r * 256 + tid;
    int v = read_mask(mask, mbase + a, is8);
    float x = cb[a*3+0], y = cb[a*3+1], z = cb[a*3+2];
    float S = fmaf(z, z, fmaf(y, y, x * x));
    unsigned long long bal = __ballot(v != 0);
    int base = 0;
    if (lane == 0) base = atomicAdd(&s_cnt, __popcll(bal));
    base = __shfl(base, 0);
    int pos = base + __popcll(bal & ((1ull << lane) - 1ull));
    if (v) {
      float4 p; p.x = x; p.y = y; p.z = z; p.w = S;
      pts[pos] = p;
    }
    posof[a] = v ? pos : -1;
  }
  __syncthreads();
  const int cnt = s_cnt;

  // 8 lanes per query: lane = qi + 8*part
  const int qi = lane & 7;
  const int part = lane >> 3;
  const int qlocal = qchunk * 32 + wv * 8 + qi;
  const float qx = cb[qlocal*3+0], qy = cb[qlocal*3+1], qz = cb[qlocal*3+2];
  const float Q = fmaf(qz, qz, fmaf(qy, qy, qx * qx));
  const float m2x = -2.0f * qx, m2y = -2.0f * qy, m2z = -2.0f * qz;
  const int selfpos = posof[qlocal];
  const int lo = (cnt * part) >> 3;
  const int hi = (cnt * (part + 1)) >> 3;

  float t[16];
  #pragma unroll
  for (int i = 0; i < 16; ++i) t[i] = 3.0e38f;

  const int len = hi - lo;
  const int ng = (len + 7) >> 3;
  for (int g = 0; g < ng; ++g) {
    const int base = lo + g * 8;
    float s[8];
    #pragma unroll
    for (int i = 0; i < 8; ++i) {
      int idx = base + i;
      float4 p = pts[idx];
      // d' = |p|^2 - 2 q.p  (= d^2 - Q, order-preserving)
      float d = fmaf(p.z, m2z, fmaf(p.y, m2y, fmaf(p.x, m2x, p.w)));
      d = (idx == selfpos) ? 3.0e38f : d;   // exclude self
      s[i] = (idx < hi) ? d : 3.0e38f;      // ragged-tail poison
    }
    // Batcher sort-8 (19 CE)
    #define CES(i,j) { float mn_ = VMIN(s[i], s[j]); float mx_ = VMAX(s[i], s[j]); s[i] = mn_; s[j] = mx_; }
    CES(0,1) CES(2,3) CES(4,5) CES(6,7)
    CES(0,2) CES(1,3) CES(4,6) CES(5,7)
    CES(1,2) CES(5,6)
    CES(0,4) CES(1,5) CES(2,6) CES(3,7)
    CES(2,4) CES(3,5)
    CES(1,2) CES(3,4) CES(5,6)
    #undef CES
    // half-clean: t[8..15] vs reversed s  -> t becomes bitonic, holds 16 smallest
    #pragma unroll
    for (int i = 0; i < 8; ++i) t[8 + i] = VMIN(t[8 + i], s[7 - i]);
    // bitonic clean of 16
    #define CET(i,j) { float mn_ = VMIN(t[i], t[j]); float mx_ = VMAX(t[i], t[j]); t[i] = mn_; t[j] = mx_; }
    CET(0,8) CET(1,9) CET(2,10) CET(3,11) CET(4,12) CET(5,13) CET(6,14) CET(7,15)
    CET(0,4) CET(1,5) CET(2,6)  CET(3,7)  CET(8,12) CET(9,13) CET(10,14) CET(11,15)
    CET(0,2) CET(1,3) CET(4,6)  CET(5,7)  CET(8,10) CET(9,11) CET(12,14) CET(13,15)
    CET(0,1) CET(2,3) CET(4,5)  CET(6,7)  CET(8,9)  CET(10,11) CET(12,13) CET(14,15)
    #undef CET
  }

  // merge the 8 part-lists: bitonic merges with partners ^8, ^16, ^32
  #pragma unroll
  for (int stepi = 0; stepi < 3; ++stepi) {
    const int step = 8 << stepi;
    float o_[16], m[16];
    #pragma unroll
    for (int i = 0; i < 16; ++i) o_[i] = __shfl(t[i], lane ^ step);
    #pragma unroll
    for (int i = 0; i < 16; ++i) m[i] = VMIN(t[i], o_[15 - i]);
    #define CE(i,jj) { float a_ = VMIN(m[i], m[jj]); float b_ = VMAX(m[i], m[jj]); m[i] = a_; m[jj] = b_; }
    CE(0,8) CE(1,9) CE(2,10) CE(3,11) CE(4,12) CE(5,13) CE(6,14) CE(7,15)
    CE(0,4) CE(1,5) CE(2,6)  CE(3,7)  CE(8,12) CE(9,13) CE(10,14) CE(11,15)
    CE(0,2) CE(1,3) CE(4,6)  CE(5,7)  CE(8,10) CE(9,11) CE(12,14) CE(13,15)
    CE(0,1) CE(2,3) CE(4,5)  CE(6,7)  CE(8,9)  CE(10,11) CE(12,13) CE(14,15)
    #undef CE
    #pragma unroll
    for (int i = 0; i < 16; ++i) t[i] = m[i];
  }

  if (part == 0) {
    int mq = read_mask(mask, mbase + qlocal, is8);
    float res[16];
    #pragma unroll
    for (int i = 0; i < 16; ++i) {
      float v = t[i];
      float d = (v > 1.0e37f) ? 24.0f : sqrtf(fmaxf(v + Q, 1e-12f)); // pad -> MAX_DIST
      res[i] = mq ? d : -1.0f;   // -1 sentinel => output row forced to zero
    }
    float4* dst = (float4*)(dists + (size_t)(mbase + qlocal) * KTOP);
    float4 o0, o1, o2, o3;
    o0.x=res[0];  o0.y=res[1];  o0.z=res[2];  o0.w=res[3];
    o1.x=res[4];  o1.y=res[5];  o1.z=res[6];  o1.w=res[7];
    o2.x=res[8];  o2.y=res[9];  o2.z=res[10]; o2.w=res[11];
    o3.x=res[12]; o3.y=res[13]; o3.z=res[14]; o3.w=res[15];
    dst[0]=o0; dst[1]=o1; dst[2]=o2; dst[3]=o3;
  }
}

// ---------------- kernel 2: fused RBF + projection (bf16 MFMA) ----------------
// grid: (2 n-blocks, QTOT/128 m-blocks) x 256 threads (4 waves).
// Epilogue: accumulators staged through C_sh, then written tid-LINEAR so each
// store instruction covers full contiguous 128B lines (memcpy-shaped stream) —
// all MFMA-fragment-shaped store patterns measured 2x WRITE + output FETCH.
constexpr double SPd = 24.0 / 31.0;
constexpr double SP2d = SPd * SPd;
constexpr float ALPHA = (float)(-(SP2d / (SP2d + 1e-8)) * 1.4426950408889634);
constexpr float INV_SP = (float)(1.0 / SPd);

__device__ __forceinline__ void gen_tile(u32x4 (*Abuf)[1040], int row0, int s,
                                         float d0, float d1) {
  float dd0 = (d0 < 0.f) ? 1.0e9f : d0;   // sentinel -> rbf == 0
  float dd1 = (d1 < 0.f) ? 1.0e9f : d1;
  #pragma unroll
  for (int i = 0; i < 2; ++i) {
    float d = i ? dd1 : dd0;
    float u = d * INV_SP;
    float C1 = (-2.0f * ALPHA) * u;
    float C0 = ALPHA * u * u;
    #pragma unroll
    for (int c8 = 0; c8 < 4; ++c8) {
      u32x4 ch;
      #pragma unroll
      for (int q = 0; q < 4; ++q) {
        const int j0 = c8 * 8 + q * 2;
        float e0 = EXP2(fmaf(C1, (float)j0,       C0) + ALPHA * (float)(j0 * j0));
        float e1 = EXP2(fmaf(C1, (float)(j0 + 1), C0) + ALPHA * (float)((j0 + 1) * (j0 + 1)));
        ch[q] = pack2(e0, e1);
      }
      Abuf[i][s * 65 + c8 * 16 + row0] = ch;
    }
  }
}

__global__ __launch_bounds__(256, 3) void rbf_gemm_kernel(
    const float* __restrict__ dists, const float* __restrict__ W,
    float* __restrict__ out)
{
  __shared__ u32x4 A_sh[2][1040];    // [row-half][s*65 + fragslot]
  __shared__ float C_sh[32][132];    // output tile transpose buffer (+4 pad)

  const int tid = threadIdx.x;
  const int lane = tid & 63;
  const int wv = tid >> 6;
  const int c0 = blockIdx.x * 128 + wv * 32 + (lane & 15);
  const int ksub = (lane >> 4) * 8;

  // preload W fragments for 2 col-sets (MFMA B operand; n = out col)
  s16x8 bf0[16], bf1[16];
  const float* wr0 = W + (size_t)c0 * FDIM;
  const float* wr1 = wr0 + (size_t)16 * FDIM;
  #pragma unroll
  for (int s = 0; s < 16; ++s) {
    const float4* p0 = (const float4*)(wr0 + s * 32 + ksub);
    const float4* p1 = (const float4*)(wr1 + s * 32 + ksub);
    float4 a = p0[0], b = p0[1], c = p1[0], d = p1[1];
    u32x4 u0, u1;
    u0[0] = pack2(a.x, a.y); u0[1] = pack2(a.z, a.w);
    u0[2] = pack2(b.x, b.y); u0[3] = pack2(b.z, b.w);
    u1[0] = pack2(c.x, c.y); u1[1] = pack2(c.z, c.w);
    u1[2] = pack2(d.x, d.y); u1[3] = pack2(d.z, d.w);
    __builtin_memcpy(&bf0[s], &u0, sizeof(u0));
    __builtin_memcpy(&bf1[s], &u1, sizeof(u1));
  }

  const int row0 = tid >> 4;       // gen cell: row (and row+16), slot
  const int sgen = tid & 15;
  const int qbase0 = blockIdx.y * (32 * TTILES);
  const size_t dbase = (size_t)qbase0 * KTOP;

  float n0 = dists[dbase + tid];
  float n1 = dists[dbase + 256 + tid];

  for (int t = 0; t < TTILES; ++t) {
    gen_tile(A_sh, row0, sgen, n0, n1);
    if (t + 1 < TTILES) {
      n0 = dists[dbase + (size_t)(t + 1) * 512 + tid];
      n1 = dists[dbase + (size_t)(t + 1) * 512 + 256 + tid];
    }
    __syncthreads();

    f32x4 acc00 = {0.f,0.f,0.f,0.f}, acc01 = {0.f,0.f,0.f,0.f};
    f32x4 acc10 = {0.f,0.f,0.f,0.f}, acc11 = {0.f,0.f,0.f,0.f};
    #pragma unroll
    for (int s = 0; s < 16; ++s) {
      s16x8 a0, a1;
      u32x4 ra0 = A_sh[0][s * 65 + lane];
      u32x4 ra1 = A_sh[1][s * 65 + lane];
      __builtin_memcpy(&a0, &ra0, sizeof(ra0));
      __builtin_memcpy(&a1, &ra1, sizeof(ra1));
      // rbf as A (m = out row), W as B (n = out col)
      acc00 = __builtin_amdgcn_mfma_f32_16x16x32_bf16(a0, bf0[s], acc00, 0, 0, 0);
      acc01 = __builtin_amdgcn_mfma_f32_16x16x32_bf16(a0, bf1[s], acc01, 0, 0, 0);
      acc10 = __builtin_amdgcn_mfma_f32_16x16x32_bf16(a1, bf0[s], acc10, 0, 0, 0);
      acc11 = __builtin_amdgcn_mfma_f32_16x16x32_bf16(a1, bf1[s], acc11, 0, 0, 0);
    }

    // D layout: col = lane&15, row = (lane>>4)*4 + reg. Park in C_sh.
    const int rb = (lane >> 4) * 4;
    const int cw = wv * 32 + (lane & 15);   // col within block's 128
    #pragma unroll
    for (int r = 0; r < 4; ++r) {
      C_sh[rb + r][cw]           = acc00[r];
      C_sh[rb + r][cw + 16]      = acc01[r];
      C_sh[16 + rb + r][cw]      = acc10[r];
      C_sh[16 + rb + r][cw + 16] = acc11[r];
    }
    __syncthreads();   // C_sh complete; A_sh reads also complete -> safe

    // tid-linear write-out: each 32-lane group covers 512 contiguous bytes
    const int qbase = qbase0 + t * 32;
    const int orow = tid >> 5;          // 0..7
    const int ocol = (tid & 31) * 4;    // 0..124
    float* obase = out + (size_t)qbase * ODIM + blockIdx.x * 128 + ocol;
    #pragma unroll
    for (int k = 0; k < 4; ++k) {
      int row = orow + k * 8;
      f32x4 v = *(const f32x4*)&C_sh[row][ocol];
      *(f32x4*)(obase + (size_t)row * ODIM) = v;
    }
    // next tile's gen_tile(A_sh) writes are fenced by the next iteration's
    // __syncthreads(); C_sh rewrite is fenced by that same barrier.
  }
}

extern "C" void kernel_launch(void* const* d_in, const int* in_sizes, int n_in,
                              void* d_out, int out_size, void* d_ws, size_t ws_size,
                              hipStream_t stream) {
  const float* coords = (const float*)d_in[0];
  const void* mask = d_in[1];
  const float* W = (const float*)d_in[2];
  float* out = (float*)d_out;
  float* dists = (float*)d_ws;   // QTOT * 16 fp32 = 4 MB scratch

  hipLaunchKernelGGL(topk_kernel, dim3(QTOT / 32), dim3(256), 0, stream,
                     coords, mask, dists);
  hipLaunchKernelGGL(rbf_gemm_kernel, dim3(2, QTOT / (32 * TTILES)), dim3(256), 0, stream,
                     dists, W, out);
}